// Round 1
// baseline (9748.147 us; speedup 1.0000x reference)
//
#include <hip/hip_runtime.h>
#include <math.h>

#define BB 64      // batch
#define SS 512     // seq len
#define EE 128     // embed dim
#define HH 256     // hidden
#define NC 9       // classes
#define G4 1024    // 4*H gates

// ---------- activations (overflow-safe, fast) ----------
__device__ __forceinline__ float sigf(float x) {
    return 1.0f / (1.0f + __expf(-x));   // x<<0: expf->inf -> 0; x>>0: ->1
}
__device__ __forceinline__ float tanhfast(float x) {
    float a = fabsf(x);
    float e = __expf(-2.0f * a);         // e in (0,1]
    float t = (1.0f - e) / (1.0f + e);
    return copysignf(t, x);
}

// ---------- transpose w_hh -> wT[dir][k4][j][4] for coalesced f4 loads ----------
__global__ void transpose_whh(const float* __restrict__ whh, float* __restrict__ wT) {
    // whh: [2][1024][256] ; wT: [2][64][1024][4]
    int idx = blockIdx.x * 256 + threadIdx.x;        // over 2*64*1024
    if (idx >= 2 * 64 * 1024) return;
    int jj  = idx & 1023;
    int k4  = (idx >> 10) & 63;
    int dir = idx >> 16;
    float4 v = *(const float4*)(whh + ((long)(dir * 1024 + jj)) * 256 + (k4 << 2));
    *(float4*)(wT + (((long)(dir * 64 + k4)) * 1024 + jj) * 4) = v;
}

// ---------- tiled f32 GEMM: out[m][n] = A[row(m)][:] . W[n][:] + bias[n] ----------
// BM=BN=128, BK=8, 256 threads, 8x8 microtile.
template <int KDIM, bool GATHER>
__global__ __launch_bounds__(256) void gemm_xg(
    const float* __restrict__ A,        // GATHER: emb (V,128) ; else H0 (B*S,512)
    const int*   __restrict__ tokens,   // B*S (GATHER only)
    const float* __restrict__ W,        // (1024, KDIM) row-major
    const float* __restrict__ bias,     // (1024)
    float* __restrict__ out,            // (B*Tc, 1024)
    int TcLog, int t_base, int t_sign)
{
    __shared__ float As[8][128];
    __shared__ float Bs[8][132];
    int m0 = blockIdx.x * 128;
    int n0 = blockIdx.y * 128;
    int tid = threadIdx.x;
    int tm = tid >> 4, tn = tid & 15;
    float acc[8][8];
    #pragma unroll
    for (int i = 0; i < 8; i++)
        #pragma unroll
        for (int j = 0; j < 8; j++) acc[i][j] = 0.f;

    int ml = tid >> 1;
    int khalf = (tid & 1) * 4;
    // map chunk-row -> global sequence row
    int mload = m0 + ml;
    int tc = mload & ((1 << TcLog) - 1);
    int b  = mload >> TcLog;
    int tglob = t_base + t_sign * tc;
    long arow = (long)b * SS + tglob;
    const float* Aptr = GATHER ? (A + (long)tokens[arow] * EE)
                               : (A + arow * (long)KDIM);
    const float* Wp = W + (long)(n0 + ml) * KDIM + khalf;

    for (int k0 = 0; k0 < KDIM; k0 += 8) {
        float4 av = *(const float4*)(Aptr + k0 + khalf);
        float4 bv = *(const float4*)(Wp + k0);
        As[khalf + 0][ml] = av.x; As[khalf + 1][ml] = av.y;
        As[khalf + 2][ml] = av.z; As[khalf + 3][ml] = av.w;
        Bs[khalf + 0][ml] = bv.x; Bs[khalf + 1][ml] = bv.y;
        Bs[khalf + 2][ml] = bv.z; Bs[khalf + 3][ml] = bv.w;
        __syncthreads();
        #pragma unroll
        for (int kk = 0; kk < 8; kk++) {
            float a[8], w[8];
            *(float4*)&a[0] = *(const float4*)&As[kk][tm * 8];
            *(float4*)&a[4] = *(const float4*)&As[kk][tm * 8 + 4];
            *(float4*)&w[0] = *(const float4*)&Bs[kk][tn * 8];
            *(float4*)&w[4] = *(const float4*)&Bs[kk][tn * 8 + 4];
            #pragma unroll
            for (int i = 0; i < 8; i++)
                #pragma unroll
                for (int j = 0; j < 8; j++) acc[i][j] = fmaf(a[i], w[j], acc[i][j]);
        }
        __syncthreads();
    }
    #pragma unroll
    for (int i = 0; i < 8; i++) {
        int m = m0 + tm * 8 + i;
        float* op = out + (long)m * G4 + n0 + tn * 8;
        #pragma unroll
        for (int j = 0; j < 8; j++) op[j] = acc[i][j] + bias[n0 + tn * 8 + j];
    }
}

// ---------- LSTM scan: 1 block = 2 batch rows x 1 direction, 1024 threads ----------
__global__ __launch_bounds__(1024) void lstm_scan(
    const float* __restrict__ xgF, const float* __restrict__ xgB, // [B][Tc][1024]
    const float* __restrict__ wT,     // [2][64][1024][4]
    const float* __restrict__ bhh2,   // [2][1024]
    float* __restrict__ hout,         // [B*S][512]  (fwd cols 0..255, bwd 256..511)
    float* __restrict__ state,        // [2][B][2][256]  ({h,c})
    int Tc, int t_base_f, int t_base_b, int doInit)
{
    int dir = blockIdx.y;
    int b0 = blockIdx.x * 2, b1 = b0 + 1;
    const float* xg = dir ? xgB : xgF;
    int t_base = dir ? t_base_b : t_base_f;
    int t_sign = dir ? -1 : 1;
    const float* wT4 = wT + (long)dir * 64 * 1024 * 4;
    int j = threadIdx.x;

    __shared__ float2 hp[HH];          // {h_b0[k], h_b1[k]}
    __shared__ float g[2][G4];

    int bb = j >> 8, k = j & 255;      // valid for j<512
    float c_reg = 0.f;
    if (doInit) {
        if (j < HH) hp[j] = make_float2(0.f, 0.f);
    } else {
        if (j < HH) hp[j] = make_float2(state[((dir * BB + b0) * 2 + 0) * HH + j],
                                        state[((dir * BB + b1) * 2 + 0) * HH + j]);
        if (j < 512) c_reg = state[((dir * BB + (bb ? b1 : b0)) * 2 + 1) * HH + k];
    }
    float bj = bhh2[dir * G4 + j];
    __syncthreads();

    for (int tc = 0; tc < Tc; ++tc) {
        int t = t_base + t_sign * tc;
        float acc0 = xg[((long)(b0 * Tc + tc)) * G4 + j] + bj;
        float acc1 = xg[((long)(b1 * Tc + tc)) * G4 + j] + bj;
        const float4* hp4 = (const float4*)hp;
        #pragma unroll 8
        for (int k4 = 0; k4 < 64; ++k4) {
            float4 w  = *(const float4*)(wT4 + ((long)k4 * G4 + j) * 4);
            float4 pA = hp4[k4 * 2 + 0];   // {h0[4k4],h1[4k4],h0[4k4+1],h1[4k4+1]}
            float4 pB = hp4[k4 * 2 + 1];
            acc0 = fmaf(w.x, pA.x, acc0); acc1 = fmaf(w.x, pA.y, acc1);
            acc0 = fmaf(w.y, pA.z, acc0); acc1 = fmaf(w.y, pA.w, acc1);
            acc0 = fmaf(w.z, pB.x, acc0); acc1 = fmaf(w.z, pB.y, acc1);
            acc0 = fmaf(w.w, pB.z, acc0); acc1 = fmaf(w.w, pB.w, acc1);
        }
        g[0][j] = acc0;
        g[1][j] = acc1;
        __syncthreads();
        if (j < 512) {
            float gi = g[bb][k], gf = g[bb][k + 256], gg = g[bb][k + 512], go = g[bb][k + 768];
            c_reg = sigf(gf) * c_reg + sigf(gi) * tanhfast(gg);
            float h = sigf(go) * tanhfast(c_reg);
            ((float*)&hp[k])[bb] = h;
            int bsel = bb ? b1 : b0;
            hout[((long)(bsel * SS + t)) * 512 + dir * 256 + k] = h;
        }
        __syncthreads();
    }
    if (j < 512) {
        int bsel = bb ? b1 : b0;
        state[((dir * BB + bsel) * 2 + 0) * HH + k] = ((float*)&hp[k])[bb];
        state[((dir * BB + bsel) * 2 + 1) * HH + k] = c_reg;
    }
}

// ---------- emissions: em[m][c] = h1[m][:512].cls_w[c] + cls_b[c] ----------
__global__ __launch_bounds__(256) void emissions_k(
    const float* __restrict__ h1, const float* __restrict__ clsw,
    const float* __restrict__ clsb, float* __restrict__ em)
{
    long u = (long)blockIdx.x * 256 + threadIdx.x;
    if (u >= (long)BB * SS * NC) return;
    int c = (int)(u % NC);
    long m = u / NC;
    const float4* hr = (const float4*)(h1 + m * 512);
    const float4* wr = (const float4*)(clsw + (long)c * 512);
    float s0 = 0, s1 = 0, s2 = 0, s3 = 0;
    #pragma unroll 8
    for (int q = 0; q < 128; q += 4) {
        float4 a0 = hr[q],     w0 = wr[q];
        float4 a1 = hr[q + 1], w1 = wr[q + 1];
        float4 a2 = hr[q + 2], w2 = wr[q + 2];
        float4 a3 = hr[q + 3], w3 = wr[q + 3];
        s0 += a0.x * w0.x + a0.y * w0.y + a0.z * w0.z + a0.w * w0.w;
        s1 += a1.x * w1.x + a1.y * w1.y + a1.z * w1.z + a1.w * w1.w;
        s2 += a2.x * w2.x + a2.y * w2.y + a2.z * w2.z + a2.w * w2.w;
        s3 += a3.x * w3.x + a3.y * w3.y + a3.z * w3.z + a3.w * w3.w;
    }
    em[u] = (s0 + s1) + (s2 + s3) + clsb[c];
}

// ---------- CRF log-likelihood per batch row (1 wave / row) ----------
__global__ __launch_bounds__(64) void crf_llh(
    const float* __restrict__ em, const int* __restrict__ labels,
    const int* __restrict__ mask, const float* __restrict__ start,
    const float* __restrict__ endt, const float* __restrict__ trans,
    float* __restrict__ llh)
{
    int b = blockIdx.x, j = threadIdx.x;
    bool act = j < NC;
    float tcol[NC];
    #pragma unroll
    for (int i = 0; i < NC; i++) tcol[i] = act ? trans[i * NC + j] : 0.f;
    const float* emb_ = em + (long)b * SS * NC;
    const int* lb = labels + b * SS;
    const int* mk = mask + b * SS;
    float alpha = act ? (start[j] + emb_[j]) : -1e30f;

    // numerator: lane-parallel over t
    float num = 0.f;
    int msum = 0;
    for (int t = j; t < SS; t += 64) msum += (mk[t] != 0);
    for (int t = 1 + j; t < SS; t += 64) {
        float m = (float)mk[t];
        num += m * (trans[lb[t - 1] * NC + lb[t]] + emb_[t * NC + lb[t]]);
    }
    for (int o = 32; o > 0; o >>= 1) {
        num  += __shfl_down(num, o);
        msum += __shfl_down(msum, o);
    }
    msum = __shfl(msum, 0);

    // alpha recursion
    for (int t = 1; t < SS; t++) {
        int m = mk[t];
        float emj = act ? emb_[t * NC + j] : 0.f;
        float v[NC];
        float mx = -1e30f;
        #pragma unroll
        for (int i = 0; i < NC; i++) {
            v[i] = __shfl(alpha, i) + tcol[i];
            mx = fmaxf(mx, v[i]);
        }
        float sum = 0.f;
        #pragma unroll
        for (int i = 0; i < NC; i++) sum += __expf(v[i] - mx);
        float nxt = mx + __logf(sum) + emj;
        if (m > 0 && act) alpha = nxt;
    }
    float fin = act ? alpha + endt[j] : -1e30f;
    float mx = -1e30f;
    #pragma unroll
    for (int i = 0; i < NC; i++) mx = fmaxf(mx, __shfl(fin, i));
    float s = 0.f;
    #pragma unroll
    for (int i = 0; i < NC; i++) s += __expf(__shfl(fin, i) - mx);
    float den = mx + __logf(s);
    if (j == 0) {
        int last_idx = msum - 1;
        float numer = num + start[lb[0]] + emb_[lb[0]] + endt[lb[last_idx]];
        llh[b] = numer - den;
    }
}

__global__ __launch_bounds__(64) void loss_k(const float* __restrict__ llh, float* __restrict__ out) {
    int j = threadIdx.x;
    float v = llh[j];
    for (int o = 32; o > 0; o >>= 1) v += __shfl_down(v, o);
    if (j == 0) out[0] = -v / 64.0f;
}

// ---------- Viterbi per batch row (1 wave / row, backpointers in LDS) ----------
__global__ __launch_bounds__(64) void viterbi_k(
    const float* __restrict__ em, const int* __restrict__ mask,
    const float* __restrict__ start, const float* __restrict__ endt,
    const float* __restrict__ trans, float* __restrict__ outp)
{
    int b = blockIdx.x, j = threadIdx.x;
    bool act = j < NC;
    __shared__ unsigned char bp[SS][NC];
    float tcol[NC];
    #pragma unroll
    for (int i = 0; i < NC; i++) tcol[i] = act ? trans[i * NC + j] : 0.f;
    const float* emb_ = em + (long)b * SS * NC;
    const int* mk = mask + b * SS;
    float score = act ? (start[j] + emb_[j]) : -1e30f;

    for (int t = 1; t < SS; t++) {
        float best = 0.f;
        int bi = 0;
        #pragma unroll
        for (int i = 0; i < NC; i++) {
            float vv = __shfl(score, i) + tcol[i];
            if (i == 0 || vv > best) { best = vv; bi = i; }   // first-max (jnp.argmax)
        }
        int m = mk[t];
        float nxt = best + (act ? emb_[t * NC + j] : 0.f);
        if (act) {
            if (m > 0) { score = nxt; bp[t][j] = (unsigned char)bi; }
            else       { bp[t][j] = (unsigned char)j; }
        }
    }
    // last = argmax(score + end), first-max
    float fin = act ? score + endt[j] : -1e30f;
    float bestf = 0.f;
    int last = 0;
    #pragma unroll
    for (int i = 0; i < NC; i++) {
        float vv = __shfl(fin, i);
        if (i == 0 || vv > bestf) { bestf = vv; last = i; }
    }
    __syncthreads();
    if (j == 0) {
        int cur = last;
        outp[1 + (long)b * SS + (SS - 1)] = (float)cur;
        for (int t = SS - 1; t >= 1; t--) {
            cur = bp[t][cur];
            outp[1 + (long)b * SS + (t - 1)] = (float)cur;
        }
    }
}

extern "C" void kernel_launch(void* const* d_in, const int* in_sizes, int n_in,
                              void* d_out, int out_size, void* d_ws, size_t ws_size,
                              hipStream_t stream) {
    const int*   tok    = (const int*)d_in[0];
    const int*   lab    = (const int*)d_in[1];
    const int*   msk    = (const int*)d_in[2];
    const float* emb    = (const float*)d_in[3];
    const float* w_ih0  = (const float*)d_in[4];   // (2,1024,128)
    const float* w_hh0  = (const float*)d_in[5];   // (2,1024,256)
    const float* b_ih0  = (const float*)d_in[6];   // (2,1024)
    const float* b_hh0  = (const float*)d_in[7];
    const float* w_ih1  = (const float*)d_in[8];   // (2,1024,512)
    const float* w_hh1  = (const float*)d_in[9];
    const float* b_ih1  = (const float*)d_in[10];
    const float* b_hh1  = (const float*)d_in[11];
    const float* clsw   = (const float*)d_in[12];  // (9,512)
    const float* clsb   = (const float*)d_in[13];
    const float* startt = (const float*)d_in[14];
    const float* endt   = (const float*)d_in[15];
    const float* transm = (const float*)d_in[16];
    float* out = (float*)d_out;

    // ---- workspace carve (f32 elements) ----
    size_t nH  = (size_t)BB * SS * 512;            // 16.78M each
    size_t nWT = (size_t)2 * 64 * 1024 * 4;        // 0.52M per layer
    size_t nEM = (size_t)BB * SS * NC;
    size_t nST = (size_t)2 * BB * 2 * HH;
    size_t fixedN = nH * 2 + nWT * 2 + nEM + nST + 64;
    int TcLog = 9;
    for (; TcLog > 5; --TcLog) {
        size_t tot = (fixedN + 2 * ((size_t)BB << TcLog) * 1024) * 4;
        if (tot <= ws_size) break;
    }
    int Tc = 1 << TcLog;
    size_t nXG = ((size_t)BB << TcLog) * 1024;

    float* H0  = (float*)d_ws;
    float* H1  = H0 + nH;
    float* WT0 = H1 + nH;
    float* WT1 = WT0 + nWT;
    float* EM  = WT1 + nWT;
    float* ST  = EM + nEM;
    float* LLH = ST + nST;
    float* XGF = LLH + 64;
    float* XGB = XGF + nXG;

    transpose_whh<<<512, 256, 0, stream>>>(w_hh0, WT0);
    transpose_whh<<<512, 256, 0, stream>>>(w_hh1, WT1);

    int nCh = SS >> TcLog;
    dim3 gg((BB << TcLog) / 128, 1024 / 128);

    // ---- layer 0 ----
    for (int c = 0; c < nCh; c++) {
        int tbF = c * Tc;
        int tbB = SS - 1 - c * Tc;
        gemm_xg<128, true><<<gg, 256, 0, stream>>>(emb, tok, w_ih0,               b_ih0,        XGF, TcLog, tbF, +1);
        gemm_xg<128, true><<<gg, 256, 0, stream>>>(emb, tok, w_ih0 + 1024 * 128,  b_ih0 + 1024, XGB, TcLog, tbB, -1);
        lstm_scan<<<dim3(32, 2), 1024, 0, stream>>>(XGF, XGB, WT0, b_hh0, H0, ST, Tc, tbF, tbB, c == 0);
    }
    // ---- layer 1 ----
    for (int c = 0; c < nCh; c++) {
        int tbF = c * Tc;
        int tbB = SS - 1 - c * Tc;
        gemm_xg<512, false><<<gg, 256, 0, stream>>>(H0, nullptr, w_ih1,              b_ih1,        XGF, TcLog, tbF, +1);
        gemm_xg<512, false><<<gg, 256, 0, stream>>>(H0, nullptr, w_ih1 + 1024 * 512, b_ih1 + 1024, XGB, TcLog, tbB, -1);
        lstm_scan<<<dim3(32, 2), 1024, 0, stream>>>(XGF, XGB, WT1, b_hh1, H1, ST, Tc, tbF, tbB, c == 0);
    }

    emissions_k<<<((BB * SS * NC) + 255) / 256, 256, 0, stream>>>(H1, clsw, clsb, EM);
    crf_llh<<<BB, 64, 0, stream>>>(EM, lab, msk, startt, endt, transm, LLH);
    loss_k<<<1, 64, 0, stream>>>(LLH, out);
    viterbi_k<<<BB, 64, 0, stream>>>(EM, msk, startt, endt, transm, out);
}